// Round 3
// baseline (2156.571 us; speedup 1.0000x reference)
//
#include <hip/hip_runtime.h>

#define IN_CAPS 1152
#define OUT_CH  32
#define BLOCK   576                       // 9 waves, 2 rows/thread, uniform work
#define NWAVES  (BLOCK / 64)              // 9
#define ROW_F4  (OUT_CH / 4)              // 8 float4 per row
#define TILE_F4 (IN_CAPS * ROW_F4)        // 9216 float4 = 147,456 B
#define CPW     (TILE_F4 / (64 * NWAVES)) // 16 staging chunks per wave
#define EPS 1e-8f

__device__ __forceinline__ float rfl(float x) {
    return __uint_as_float(__builtin_amdgcn_readfirstlane(__float_as_uint(x)));
}

// raw barrier with LDS-only drain: does NOT wait vmcnt -> prefetch stays in flight
__device__ __forceinline__ void lgkm0_barrier() {
    asm volatile("s_waitcnt lgkmcnt(0)" ::: "memory");
    __builtin_amdgcn_s_barrier();
}

// butterfly (verified absmax=0 in prior rounds) + cross-wave reduce + squash -> vsh
__device__ __forceinline__ void reduce_squash(float acc[OUT_CH],
                                              float* __restrict__ swred,
                                              float* __restrict__ vsh,
                                              const int t, const int lane, const int wave)
{
    #pragma unroll
    for (int st = 0; st < 5; ++st) {
        const int m    = 1 << st;
        const int half = 16 >> st;
        const bool up  = (lane & m) != 0;
        #pragma unroll
        for (int j = 0; j < half; ++j) {
            const float send = up ? acc[j] : acc[half + j];
            const float keep = up ? acc[half + j] : acc[j];
            acc[j] = keep + __shfl_xor(send, m);
        }
    }
    acc[0] += __shfl_xor(acc[0], 32);

    const int l5 = lane & 31;
    const int ch = ((l5 & 1) << 4) | ((l5 & 2) << 2) | (l5 & 4)
                 | ((l5 & 8) >> 2) | ((l5 & 16) >> 4);      // bitrev5: lane -> channel
    if (lane < 32) swred[wave * OUT_CH + ch] = acc[0];
    lgkm0_barrier();
    if (t < OUT_CH) {
        float s = 0.f;
        #pragma unroll
        for (int w = 0; w < NWAVES; ++w) s += swred[w * OUT_CH + t];
        float n2 = s * s;
        #pragma unroll
        for (int m2 = 1; m2 <= 16; m2 <<= 1) n2 += __shfl_xor(n2, m2);
        const float scale = n2 / ((1.0f + n2) * sqrtf(n2 + EPS));
        vsh[t] = s * scale;
    }
    lgkm0_barrier();
}

__global__ __launch_bounds__(BLOCK)
void caps_route(const float* __restrict__ u_hat,
                const float* __restrict__ c0,
                const int* __restrict__ routings_p,
                float* __restrict__ out, int N)
{
    __shared__ float4 u_s[TILE_F4];                 // 147,456 B, XOR-swizzled layout
    __shared__ float  swred[NWAVES * OUT_CH];       // 1,152 B
    __shared__ float  vsh[OUT_CH];                  // 128 B

    const int t     = threadIdx.x;
    const int lane  = t & 63;
    const int wave  = t >> 6;
    const int lperm = lane ^ (lane >> 3);           // global-side swizzle (involution w/ read side)

    const float4* __restrict__ u4 = reinterpret_cast<const float4*>(u_hat);
    const float4* __restrict__ c4 = reinterpret_cast<const float4*>(c0);
    const int iters = routings_p[0] - 1;

    // async stage of tile nn into LDS: linear LDS dest, pre-swizzled global source (rule #21)
    auto stage = [&](int nn) {
        const float4* src = u4 + (size_t)nn * TILE_F4;
        #pragma unroll
        for (int q = 0; q < CPW; ++q) {
            const int cb = __builtin_amdgcn_readfirstlane((wave * CPW + q) * 64);
            __builtin_amdgcn_global_load_lds(
                (const __attribute__((address_space(1))) void*)(src + cb + lperm),
                (__attribute__((address_space(3))) void*)(u_s + cb),
                16, 0, 0);
        }
    };

    // prologue: stage first tile
    stage(blockIdx.x);
    asm volatile("s_waitcnt vmcnt(0)" ::: "memory");
    __builtin_amdgcn_s_barrier();

    for (int n = blockIdx.x; n < N; n += gridDim.x) {
        const int rA = t, rB = t + BLOCK;           // this thread's two rows

        // ---- rows LDS -> regs, undoing the XOR swizzle (ds_read_b128, ~conflict-free) ----
        float uA[OUT_CH], uB[OUT_CH];
        #pragma unroll
        for (int q = 0; q < ROW_F4; ++q) {
            const float4 x = u_s[rA * ROW_F4 + (q ^ (rA & 7))];
            uA[4*q+0] = x.x; uA[4*q+1] = x.y; uA[4*q+2] = x.z; uA[4*q+3] = x.w;
        }
        #pragma unroll
        for (int q = 0; q < ROW_F4; ++q) {
            const float4 x = u_s[rB * ROW_F4 + (q ^ (rB & 7))];
            uB[4*q+0] = x.x; uB[4*q+1] = x.y; uB[4*q+2] = x.z; uB[4*q+3] = x.w;
        }
        lgkm0_barrier();                            // all rows consumed; LDS free for next tile

        // ---- c0 rows -> regs, issued BEFORE staging so their wait leaves staging in flight ----
        float m[OUT_CH], cB[OUT_CH];
        {
            const float4* crA = c4 + (size_t)rA * ROW_F4;
            const float4* crB = c4 + (size_t)rB * ROW_F4;
            #pragma unroll
            for (int q = 0; q < ROW_F4; ++q) {
                const float4 x = crA[q];
                m[4*q+0] = x.x; m[4*q+1] = x.y; m[4*q+2] = x.z; m[4*q+3] = x.w;
            }
            #pragma unroll
            for (int q = 0; q < ROW_F4; ++q) {
                const float4 x = crB[q];
                cB[4*q+0] = x.x; cB[4*q+1] = x.y; cB[4*q+2] = x.z; cB[4*q+3] = x.w;
            }
        }
        __builtin_amdgcn_sched_barrier(0);          // pin: c0 issued before staging
        const int nn = n + gridDim.x;
        if (nn < N) stage(nn);                      // async; flies under passes 1-3
        __builtin_amdgcn_sched_barrier(0);          // pin: staging issued before c0 consumption

        // ---- pass 1: s[j] = sum_i u*c0 ----
        #pragma unroll
        for (int j = 0; j < OUT_CH; ++j)
            m[j] = fmaf(uA[j], m[j], uB[j] * cB[j]);
        reduce_squash(m, swred, vsh, t, lane, wave);

        // ---- routing passes: all data in regs, v broadcast via LDS -> SGPRs ----
        for (int it = 0; it < iters; ++it) {
            float v[OUT_CH];
            #pragma unroll
            for (int q = 0; q < ROW_F4; ++q) {
                const float4 x = *reinterpret_cast<const float4*>(&vsh[4 * q]);
                v[4*q+0] = rfl(x.x); v[4*q+1] = rfl(x.y);
                v[4*q+2] = rfl(x.z); v[4*q+3] = rfl(x.w);
            }
            float m2[OUT_CH];
            float sumA = 0.f, sumB = 0.f;
            // thread-local softmax per row; max-subtraction skipped (|u*v| small, fp32 exp safe)
            #pragma unroll
            for (int j = 0; j < OUT_CH; ++j) {
                const float e = __expf(uA[j] * v[j]);
                sumA += e;
                m[j] = uA[j] * e;
            }
            #pragma unroll
            for (int j = 0; j < OUT_CH; ++j) {
                const float e = __expf(uB[j] * v[j]);
                sumB += e;
                m2[j] = uB[j] * e;
            }
            const float wA = __builtin_amdgcn_rcpf(sumA);
            const float wB = __builtin_amdgcn_rcpf(sumB);
            #pragma unroll
            for (int j = 0; j < OUT_CH; ++j)
                m[j] = fmaf(m2[j], wB, m[j] * wA);
            reduce_squash(m, swred, vsh, t, lane, wave);
        }

        if (t < OUT_CH)
            out[(size_t)n * OUT_CH + t] = vsh[t] * 0.5f + 0.5f;

        // single counted drain per iteration: staging for n+1 (and out store) complete
        asm volatile("s_waitcnt vmcnt(0)" ::: "memory");
        __builtin_amdgcn_s_barrier();
    }
}

extern "C" void kernel_launch(void* const* d_in, const int* in_sizes, int n_in,
                              void* d_out, int out_size, void* d_ws, size_t ws_size,
                              hipStream_t stream) {
    const float* u_hat   = (const float*)d_in[0];
    const float* c0      = (const float*)d_in[1];
    const int*   routing = (const int*)d_in[2];
    float* out = (float*)d_out;

    const int N = in_sizes[0] / (IN_CAPS * OUT_CH);   // 4096
    const int grid = N < 256 ? N : 256;               // persistent: 1 block/CU
    caps_route<<<dim3(grid), dim3(BLOCK), 0, stream>>>(u_hat, c0, routing, out, N);
}